// Round 5
// baseline (611.091 us; speedup 1.0000x reference)
//
#include <hip/hip_runtime.h>
#include <hip/hip_bf16.h>
#include <hip/hip_fp16.h>
#include <math.h>

#define NATOMS 16384
#define NEDGE  524288
#define NINT   6
#define NGAUSS 50
#define TK     2048
#define INV_DT 128.0f    // knots at d = k/128, range [0,16)
#define DT     (1.0f/128.0f)
#define LOG2F_ 0.69314718055994530942f
#define NBUCK  512       // per graph, 32 dst atoms each

__device__ __forceinline__ float sspf(float v){
    return fmaxf(v, 0.f) + log1pf(__expf(-fabsf(v))) - LOG2F_;
}

// ---------------- h = emb[z]  (rows 0..N-1 = A, N..2N-1 = G)
__global__ __launch_bounds__(256) void k_embed(const int* __restrict__ zA, const int* __restrict__ zG,
                                               const float* __restrict__ emb, float* __restrict__ h){
    int idx = blockIdx.x * 256 + threadIdx.x;        // < 2*NATOMS*64
    int n = idx >> 6, f = idx & 63;
    int z = (n < NATOMS) ? zA[n] : zG[n - NATOMS];
    h[idx] = emb[(z << 6) + f];
}

// ---------------- histogram of dst per graph (per-atom)
__global__ __launch_bounds__(256) void k_hist(const int* __restrict__ edgeA, const int* __restrict__ edgeG,
                                              int* __restrict__ hist){
    int e = blockIdx.x * 256 + threadIdx.x;          // < 2*NEDGE
    int g = e >= NEDGE;
    int el = e - (g ? NEDGE : 0);
    const int* edge = g ? edgeG : edgeA;
    atomicAdd(&hist[g * NATOMS + edge[NEDGE + el]], 1);
}

// ---------------- exclusive scan -> per-atom rowptr + per-bucket global cursor init
__global__ __launch_bounds__(1024) void k_scan(const int* __restrict__ hist, int* __restrict__ rowptr,
                                               int* __restrict__ gcur){
    int g = blockIdx.x;
    const int* hg = hist + g * NATOMS;
    int* rp = rowptr + g * (NATOMS + 1);
    int* gc = gcur + g * NBUCK;
    __shared__ int ssum[1024];
    int t = threadIdx.x;
    int base = t * 16;
    int v[16]; int s = 0;
    #pragma unroll
    for (int j = 0; j < 16; j++){ v[j] = hg[base + j]; s += v[j]; }
    ssum[t] = s;
    __syncthreads();
    for (int off = 1; off < 1024; off <<= 1){
        int add = (t >= off) ? ssum[t - off] : 0;
        __syncthreads();
        ssum[t] += add;
        __syncthreads();
    }
    int run = ssum[t] - s;
    #pragma unroll
    for (int j = 0; j < 16; j++){
        int n = base + j;
        rp[n] = run;
        if ((n & 31) == 0) gc[n >> 5] = run;   // bucket start
        run += v[j];
    }
    if (t == 1023) rp[NATOMS] = ssum[1023];
}

// ---------------- pass 1: bucket-binned placement (coherent writes)
// meta8: m.x = src(14) | ti<<14(11) | dstlow<<25(5) ; m.y = tf (fp32)
__global__ __launch_bounds__(256) void k_place1(const int* __restrict__ edgeA, const int* __restrict__ edgeG,
                                                const float* __restrict__ posA, const float* __restrict__ posG,
                                                int* __restrict__ gcur, uint2* __restrict__ meta8){
    __shared__ unsigned int lhist[NBUCK];
    __shared__ unsigned int lbase[NBUCK];
    int blk = blockIdx.x;                    // 256 blocks: 0-127 graph A, 128-255 graph G
    int g   = blk >> 7;
    int el0 = (blk & 127) * 4096;
    const int* edge = g ? edgeG : edgeA;
    const float* pos = g ? posG : posA;
    int t = threadIdx.x;
    lhist[t] = 0; lhist[t + 256] = 0;
    __syncthreads();
    unsigned int  mx[16]; float my[16];
    unsigned short rk[16]; unsigned short bb[16];
    #pragma unroll
    for (int j = 0; j < 16; j++){
        int el = el0 + j * 256 + t;
        int src = edge[el], dst = edge[NEDGE + el];
        float dx = pos[src*3+0] - pos[dst*3+0];
        float dy = pos[src*3+1] - pos[dst*3+1];
        float dz = pos[src*3+2] - pos[dst*3+2];
        float d  = sqrtf(fmaf(dx,dx, fmaf(dy,dy, fmaf(dz,dz, 1e-12f))));
        float tp = d * INV_DT;
        int   ti = (int)tp; if (ti > TK - 2) ti = TK - 2;
        float tf = tp - (float)ti;
        int b = dst >> 5;
        bb[j] = (unsigned short)b;
        rk[j] = (unsigned short)atomicAdd(&lhist[b], 1u);
        mx[j] = (unsigned int)src | ((unsigned int)ti << 14) | ((unsigned int)(dst & 31) << 25);
        my[j] = tf;
    }
    __syncthreads();
    lbase[t]       = (unsigned int)atomicAdd(&gcur[g * NBUCK + t],       (int)lhist[t]);
    lbase[t + 256] = (unsigned int)atomicAdd(&gcur[g * NBUCK + t + 256], (int)lhist[t + 256]);
    __syncthreads();
    #pragma unroll
    for (int j = 0; j < 16; j++){
        unsigned int pos_ = lbase[bb[j]] + rk[j];
        meta8[(size_t)g * NEDGE + pos_] = make_uint2(mx[j], __float_as_uint(my[j]));
    }
}

// ---------------- pass 2: within-bucket scatter to per-dst order (L2-hot 8KB region)
// metaF: m.x = srcElem(20 = src<<6) | ti<<20(11) ; m.y = tf (fp32)
__global__ __launch_bounds__(256) void k_place2(const uint2* __restrict__ meta8, const int* __restrict__ rowptr,
                                                uint2* __restrict__ metaF){
    __shared__ int lcur[32];
    int blk = blockIdx.x;                    // 1024: g = blk>>9, bucket = blk&511
    int g = blk >> 9;
    int b = blk & (NBUCK - 1);
    const int* rp = rowptr + g * (NATOMS + 1);
    int lo = rp[b << 5], hi = rp[(b + 1) << 5];
    int t = threadIdx.x;
    if (t < 32) lcur[t] = rp[(b << 5) + t];
    __syncthreads();
    for (int idx = lo + t; idx < hi; idx += 256){
        uint2 m = meta8[(size_t)g * NEDGE + idx];
        int dstlow = (int)((m.x >> 25) & 31u);
        int p = atomicAdd(&lcur[dstlow], 1);
        unsigned int src = m.x & 16383u;
        unsigned int ti  = (m.x >> 14) & 2047u;
        metaF[(size_t)g * NEDGE + p] = make_uint2((src << 6) | (ti << 20), m.y);
    }
}

// ---------------- tabulate W_i(d)*C(d) on TK knots (fp32 scratch)
__global__ __launch_bounds__(256) void k_tables(const float* __restrict__ mw1, const float* __restrict__ mb1,
                                                const float* __restrict__ mw2, const float* __restrict__ mb2,
                                                float* __restrict__ tabf){
    int wv   = blockIdx.x * 4 + (threadIdx.x >> 6);  // < NINT*TK
    int lane = threadIdx.x & 63;
    int i = wv >> 11, k = wv & (TK - 1);
    float d = (float)k * DT;
    const float step  = 10.0f / 49.0f;
    const float coeff = -0.5f / (step * step);
    float u = mb1[(i << 6) + lane];
    #pragma unroll
    for (int gg = 0; gg < NGAUSS; gg++){
        float od = d - (float)gg * step;
        float ea = __expf(coeff * od * od);
        u = fmaf(ea, mw1[((i * NGAUSS + gg) << 6) + lane], u);
    }
    float t = sspf(u);
    float w = mb2[(i << 6) + lane];
    #pragma unroll
    for (int gg = 0; gg < 64; gg++){
        float tg = __shfl(t, gg, 64);
        w = fmaf(tg, mw2[(((i << 6) + gg) << 6) + lane], w);
    }
    float cc = 0.5f * (__cosf(d * 0.31415926535897932f) + 1.0f);
    tabf[((size_t)(i * TK + k) << 6) + lane] = w * cc;
}

// ---------------- pack interleaved half2 table: tab2[k][lane] = (Wk, Wk+1)
__global__ __launch_bounds__(256) void k_pack(const float* __restrict__ tabf, __half2* __restrict__ tab2){
    size_t idx = (size_t)blockIdx.x * 256 + threadIdx.x;   // < NINT*TK*64
    size_t rem = idx & ((size_t)TK * 64 - 1);
    float a = tabf[idx];
    float b = (rem < (size_t)TK * 64 - 64) ? tabf[idx + 64] : a;
    tab2[idx] = __floats2half2_rn(a, b);
}

// ---------------- x = h @ l1w (no bias), 64 nodes per block, fp16 output
__global__ __launch_bounds__(256) void k_lin1(const float* __restrict__ h, const float* __restrict__ w,
                                              __half* __restrict__ x){
    __shared__ float hs[64 * 65];
    __shared__ float ws_[64 * 64];
    int t = threadIdx.x;
    size_t base = (size_t)blockIdx.x * 64;
    #pragma unroll
    for (int j = 0; j < 16; j++){
        int idx = t + j * 256;
        hs[(idx >> 6) * 65 + (idx & 63)] = h[base * 64 + idx];
        ws_[idx] = w[idx];
    }
    __syncthreads();
    int te = t >> 4, tf4 = (t & 15) << 2;
    float acc[4][4];
    #pragma unroll
    for (int j = 0; j < 4; j++){ acc[j][0]=0.f; acc[j][1]=0.f; acc[j][2]=0.f; acc[j][3]=0.f; }
    for (int k = 0; k < 64; k++){
        float4 wv = *(const float4*)&ws_[(k << 6) + tf4];
        #pragma unroll
        for (int j = 0; j < 4; j++){
            float hv = hs[((te << 2) + j) * 65 + k];
            acc[j][0] = fmaf(hv, wv.x, acc[j][0]);
            acc[j][1] = fmaf(hv, wv.y, acc[j][1]);
            acc[j][2] = fmaf(hv, wv.z, acc[j][2]);
            acc[j][3] = fmaf(hv, wv.w, acc[j][3]);
        }
    }
    #pragma unroll
    for (int j = 0; j < 4; j++){
        union { __half2 h2[2]; float2 f2; } u;
        u.h2[0] = __floats2half2_rn(acc[j][0], acc[j][1]);
        u.h2[1] = __floats2half2_rn(acc[j][2], acc[j][3]);
        *(float2*)&x[(base + (te << 2) + j) * 64 + tf4] = u.f2;
    }
}

// ---------------- agg[dst] = sum_e x[src] * lerp(tab2), one wave per dst, XCD-partitioned
#define PROC(M, ACC) { \
    int xi_ = (int)((M).x & 0xFFFFFu) + lane; \
    int tb_ = (int)((M).x >> 20 << 6) + lane; \
    float tf_ = __uint_as_float((M).y); \
    float xv_ = __half2float(xg[xi_]); \
    float2 wf_ = __half22float2(tab2[tb_]); \
    (ACC) = fmaf(fmaf(wf_.y - wf_.x, tf_, wf_.x), xv_, (ACC)); }

__global__ __launch_bounds__(256) void k_agg(const __half* __restrict__ x, const __half2* __restrict__ tab2,
                                             const uint2* __restrict__ meta, const int* __restrict__ rowptr,
                                             float* __restrict__ agg){
    int b    = blockIdx.x;                 // < 2*NATOMS/4 = 8192
    int xcd  = b & 7;
    int slot = b >> 3;
    int g    = xcd >> 2;
    int bi   = (slot << 2) + (xcd & 3);    // block index within graph
    int wq   = threadIdx.x >> 6;
    int nn   = (bi << 2) + wq;             // dst atom within graph
    int lane = threadIdx.x & 63;
    const int* rp = rowptr + g * (NATOMS + 1);
    int lo = rp[nn], hi = rp[nn + 1];
    const uint2* mg = meta + (size_t)g * NEDGE;
    const __half* xg = x + ((size_t)(g ? NATOMS : 0) << 6);
    float a0 = 0.f, a1 = 0.f, a2 = 0.f, a3 = 0.f;
    int e = lo;
    if (e + 16 <= hi){
        uint2 m[16];
        #pragma unroll
        for (int j = 0; j < 16; j++) m[j] = mg[e + j];
        for (; e + 32 <= hi; e += 16){
            uint2 n[16];
            #pragma unroll
            for (int j = 0; j < 16; j++) n[j] = mg[e + 16 + j];
            #pragma unroll
            for (int j = 0; j < 16; j += 4){
                PROC(m[j+0], a0); PROC(m[j+1], a1); PROC(m[j+2], a2); PROC(m[j+3], a3);
            }
            #pragma unroll
            for (int j = 0; j < 16; j++) m[j] = n[j];
        }
        #pragma unroll
        for (int j = 0; j < 16; j += 4){
            PROC(m[j+0], a0); PROC(m[j+1], a1); PROC(m[j+2], a2); PROC(m[j+3], a3);
        }
        e += 16;
    }
    for (; e + 4 <= hi; e += 4){
        uint2 m0 = mg[e], m1 = mg[e+1], m2 = mg[e+2], m3 = mg[e+3];
        PROC(m0, a0); PROC(m1, a1); PROC(m2, a2); PROC(m3, a3);
    }
    for (; e < hi; e++){
        uint2 mm = mg[e];
        PROC(mm, a0);
    }
    agg[((size_t)(g * NATOMS + nn) << 6) + lane] = (a0 + a1) + (a2 + a3);
}

// ---------------- fused: h += ssp(agg@w2+b2)@w3+b3 ; x = h_new @ w1_next (fp16)
__global__ __launch_bounds__(256) void k_updlin(const float* __restrict__ agg, const float* __restrict__ w2,
                                                const float* __restrict__ b2, const float* __restrict__ w3,
                                                const float* __restrict__ b3, const float* __restrict__ w1n,
                                                float* __restrict__ h, __half* __restrict__ x, int has_x){
    __shared__ float bufA[64 * 65];
    __shared__ float bufT[64 * 65];
    __shared__ float bufW[64 * 64];
    int t = threadIdx.x;
    size_t base = (size_t)blockIdx.x * 64;
    #pragma unroll
    for (int j = 0; j < 16; j++){
        int idx = t + j * 256;
        bufA[(idx >> 6) * 65 + (idx & 63)] = agg[base * 64 + idx];
        bufW[idx] = w2[idx];
    }
    __syncthreads();
    int te = t >> 4, tf4 = (t & 15) << 2;
    float acc[4][4];
    #pragma unroll
    for (int j = 0; j < 4; j++){ acc[j][0]=0.f; acc[j][1]=0.f; acc[j][2]=0.f; acc[j][3]=0.f; }
    for (int k = 0; k < 64; k++){
        float4 wv = *(const float4*)&bufW[(k << 6) + tf4];
        #pragma unroll
        for (int j = 0; j < 4; j++){
            float av = bufA[((te << 2) + j) * 65 + k];
            acc[j][0] = fmaf(av, wv.x, acc[j][0]);
            acc[j][1] = fmaf(av, wv.y, acc[j][1]);
            acc[j][2] = fmaf(av, wv.z, acc[j][2]);
            acc[j][3] = fmaf(av, wv.w, acc[j][3]);
        }
    }
    float4 b2v = *(const float4*)&b2[tf4];
    #pragma unroll
    for (int j = 0; j < 4; j++){
        bufT[((te << 2) + j) * 65 + tf4 + 0] = sspf(acc[j][0] + b2v.x);
        bufT[((te << 2) + j) * 65 + tf4 + 1] = sspf(acc[j][1] + b2v.y);
        bufT[((te << 2) + j) * 65 + tf4 + 2] = sspf(acc[j][2] + b2v.z);
        bufT[((te << 2) + j) * 65 + tf4 + 3] = sspf(acc[j][3] + b2v.w);
    }
    __syncthreads();
    #pragma unroll
    for (int j = 0; j < 16; j++){
        int idx = t + j * 256;
        bufW[idx] = w3[idx];
    }
    __syncthreads();
    #pragma unroll
    for (int j = 0; j < 4; j++){ acc[j][0]=0.f; acc[j][1]=0.f; acc[j][2]=0.f; acc[j][3]=0.f; }
    for (int k = 0; k < 64; k++){
        float4 wv = *(const float4*)&bufW[(k << 6) + tf4];
        #pragma unroll
        for (int j = 0; j < 4; j++){
            float tv = bufT[((te << 2) + j) * 65 + k];
            acc[j][0] = fmaf(tv, wv.x, acc[j][0]);
            acc[j][1] = fmaf(tv, wv.y, acc[j][1]);
            acc[j][2] = fmaf(tv, wv.z, acc[j][2]);
            acc[j][3] = fmaf(tv, wv.w, acc[j][3]);
        }
    }
    float4 b3v = *(const float4*)&b3[tf4];
    #pragma unroll
    for (int j = 0; j < 4; j++){
        size_t o = (base + (te << 2) + j) * 64 + tf4;
        float4 hv = *(float4*)&h[o];
        hv.x += acc[j][0] + b3v.x;
        hv.y += acc[j][1] + b3v.y;
        hv.z += acc[j][2] + b3v.z;
        hv.w += acc[j][3] + b3v.w;
        *(float4*)&h[o] = hv;
        int r = ((te << 2) + j) * 65 + tf4;
        bufA[r + 0] = hv.x; bufA[r + 1] = hv.y; bufA[r + 2] = hv.z; bufA[r + 3] = hv.w;
    }
    if (!has_x) return;
    __syncthreads();
    #pragma unroll
    for (int j = 0; j < 16; j++){
        int idx = t + j * 256;
        bufW[idx] = w1n[idx];
    }
    __syncthreads();
    #pragma unroll
    for (int j = 0; j < 4; j++){ acc[j][0]=0.f; acc[j][1]=0.f; acc[j][2]=0.f; acc[j][3]=0.f; }
    for (int k = 0; k < 64; k++){
        float4 wv = *(const float4*)&bufW[(k << 6) + tf4];
        #pragma unroll
        for (int j = 0; j < 4; j++){
            float hv = bufA[((te << 2) + j) * 65 + k];
            acc[j][0] = fmaf(hv, wv.x, acc[j][0]);
            acc[j][1] = fmaf(hv, wv.y, acc[j][1]);
            acc[j][2] = fmaf(hv, wv.z, acc[j][2]);
            acc[j][3] = fmaf(hv, wv.w, acc[j][3]);
        }
    }
    #pragma unroll
    for (int j = 0; j < 4; j++){
        union { __half2 h2[2]; float2 f2; } u;
        u.h2[0] = __floats2half2_rn(acc[j][0], acc[j][1]);
        u.h2[1] = __floats2half2_rn(acc[j][2], acc[j][3]);
        *(float2*)&x[(base + (te << 2) + j) * 64 + tf4] = u.f2;
    }
}

// ---------------- readout: eout[g][f] = sum_n h[n][f]
__global__ __launch_bounds__(256) void k_readout(const float* __restrict__ h, float* __restrict__ eout){
    int f  = threadIdx.x & 63;
    int wq = threadIdx.x >> 6;
    int nodeBase = blockIdx.x * 256 + wq * 64;
    float acc = 0.f;
    #pragma unroll 4
    for (int j = 0; j < 64; j++) acc += h[(size_t)(nodeBase + j) * 64 + f];
    int g = nodeBase >= NATOMS;
    atomicAdd(&eout[g * 64 + f], acc);
}

// ---------------- head: fc1 -> PReLU -> fc2 -> exp
__global__ __launch_bounds__(64) void k_final(const float* __restrict__ eout, const float* __restrict__ addf,
                                              const float* __restrict__ fc1w, const float* __restrict__ fc1b,
                                              const float* __restrict__ pra, const float* __restrict__ fc2w,
                                              const float* __restrict__ fc2b, float* __restrict__ out){
    int f = threadIdx.x;
    float xv = fc1b[f];
    const float inv = 1.0f / 256.0f;
    for (int k = 0; k < 64; k++)  xv = fmaf(eout[k] * inv,      fc1w[k * 64 + f],        xv);
    for (int k = 0; k < 64; k++)  xv = fmaf(eout[64 + k] * inv, fc1w[(64 + k) * 64 + f], xv);
    xv = fmaf(addf[0], fc1w[128 * 64 + f], xv);
    xv = fmaf(addf[1], fc1w[129 * 64 + f], xv);
    float a = pra[0];
    xv = (xv >= 0.f) ? xv : a * xv;
    float s = xv * fc2w[f];
    #pragma unroll
    for (int m = 32; m >= 1; m >>= 1) s += __shfl_xor(s, m, 64);
    if (f == 0) out[0] = expf(s + fc2b[0]);
}

extern "C" void kernel_launch(void* const* d_in, const int* in_sizes, int n_in,
                              void* d_out, int out_size, void* d_ws, size_t ws_size,
                              hipStream_t stream){
    const int*   zA    = (const int*)  d_in[0];
    const float* posA  = (const float*)d_in[1];
    const int*   edgeA = (const int*)  d_in[3];
    const int*   zG    = (const int*)  d_in[4];
    const float* posG  = (const float*)d_in[5];
    const int*   edgeG = (const int*)  d_in[7];
    const float* addf  = (const float*)d_in[8];
    const float* emb   = (const float*)d_in[9];
    const float* mw1   = (const float*)d_in[10];
    const float* mb1   = (const float*)d_in[11];
    const float* mw2   = (const float*)d_in[12];
    const float* mb2   = (const float*)d_in[13];
    const float* l1w   = (const float*)d_in[14];
    const float* l2w   = (const float*)d_in[15];
    const float* l2b   = (const float*)d_in[16];
    const float* l3w   = (const float*)d_in[17];
    const float* l3b   = (const float*)d_in[18];
    const float* fc1w  = (const float*)d_in[19];
    const float* fc1b  = (const float*)d_in[20];
    const float* pra   = (const float*)d_in[21];
    const float* fc2w  = (const float*)d_in[22];
    const float* fc2b  = (const float*)d_in[23];
    float* out = (float*)d_out;

    // workspace layout (~45 MB)
    char* p = (char*)d_ws;
    auto alloc = [&](size_t bytes)->char*{ char* r = p; p += (bytes + 255) & ~(size_t)255; return r; };
    float*   tabf   = (float*)  alloc((size_t)NINT * TK * 64 * 4);   // 3.1 MB
    __half2* tab2   = (__half2*)alloc((size_t)NINT * TK * 64 * 4);   // 3.1 MB
    uint2*   meta8  = (uint2*)  alloc((size_t)2 * NEDGE * 8);        // 8.4 MB
    uint2*   metaF  = (uint2*)  alloc((size_t)2 * NEDGE * 8);        // 8.4 MB
    int*     rowptr = (int*)    alloc((size_t)2 * (NATOMS + 1) * 4);
    int*     gcur   = (int*)    alloc((size_t)2 * NBUCK * 4);
    int*     hist   = (int*)    alloc((size_t)2 * NATOMS * 4);
    float*   h      = (float*)  alloc((size_t)2 * NATOMS * 64 * 4);  // 8.4 MB
    __half*  x      = (__half*) alloc((size_t)2 * NATOMS * 64 * 2);  // 4.2 MB
    float*   agg    = (float*)  alloc((size_t)2 * NATOMS * 64 * 4);  // 8.4 MB
    float*   eout   = (float*)  alloc(128 * 4);

    hipMemsetAsync(hist, 0, (size_t)2 * NATOMS * 4, stream);
    hipMemsetAsync(eout, 0, 128 * 4, stream);

    k_embed <<<(2 * NATOMS * 64) / 256, 256, 0, stream>>>(zA, zG, emb, h);
    k_hist  <<<(2 * NEDGE) / 256,       256, 0, stream>>>(edgeA, edgeG, hist);
    k_scan  <<<2, 1024, 0, stream>>>(hist, rowptr, gcur);
    k_place1<<<256,  256, 0, stream>>>(edgeA, edgeG, posA, posG, gcur, meta8);
    k_place2<<<1024, 256, 0, stream>>>(meta8, rowptr, metaF);
    k_tables<<<(NINT * TK) / 4,        256, 0, stream>>>(mw1, mb1, mw2, mb2, tabf);
    k_pack  <<<(NINT * TK * 64) / 256, 256, 0, stream>>>(tabf, tab2);

    k_lin1<<<(2 * NATOMS) / 64, 256, 0, stream>>>(h, l1w, x);
    for (int i = 0; i < NINT; i++){
        k_agg   <<<(2 * NATOMS) / 4,  256, 0, stream>>>(x, tab2 + (size_t)i * TK * 64, metaF, rowptr, agg);
        int has_x = (i < NINT - 1);
        const float* w1n = has_x ? (l1w + (i + 1) * 4096) : l1w;
        k_updlin<<<(2 * NATOMS) / 64, 256, 0, stream>>>(agg, l2w + i * 4096, l2b + i * 64,
                                                        l3w + i * 4096, l3b + i * 64, w1n, h, x, has_x);
    }

    k_readout<<<(2 * NATOMS) / 256, 256, 0, stream>>>(h, eout);
    k_final  <<<1, 64, 0, stream>>>(eout, addf, fc1w, fc1b, pra, fc2w, fc2b, out);
}